// Round 3
// baseline (765.210 us; speedup 1.0000x reference)
//
#include <hip/hip_runtime.h>
#include <hip/hip_bf16.h>

#define N_NODES 100000
#define N_EDGES 640000
#define DIM 128
#define N_LAYERS 3
#define N_GRAPHS 128
#define N_OUT 10
#define SCAN_BLK 1024  // elements per scan block (256 thr x 4)
#define N_SCAN_BLKS ((N_NODES + SCAN_BLK - 1) / SCAN_BLK)  // 98

typedef _Float16 h4 __attribute__((ext_vector_type(4)));

struct EdgeRec { int s; float w; };  // packed (src, norm-weight)

// ---------------- degree / norm ----------------

__global__ void hist_dst(const int* __restrict__ ei, int* __restrict__ cnt) {
    int e = blockIdx.x * blockDim.x + threadIdx.x;
    if (e < N_EDGES) atomicAdd(&cnt[ei[N_EDGES + e]], 1);
}

__global__ void make_dinv(const int* __restrict__ cnt, float* __restrict__ dinv) {
    int i = blockIdx.x * blockDim.x + threadIdx.x;
    if (i < N_NODES) dinv[i] = rsqrtf((float)(cnt[i] + 1));  // +1 self-loop
}

// ---------------- exclusive scan (3 kernels) ----------------

__global__ void scan1(const int* __restrict__ cnt, int* __restrict__ off, int* __restrict__ bsum) {
    __shared__ int tmp[256];
    int base = blockIdx.x * SCAN_BLK + threadIdx.x * 4;
    int c[4];
    #pragma unroll
    for (int k = 0; k < 4; ++k) c[k] = (base + k < N_NODES) ? cnt[base + k] : 0;
    int tot = c[0] + c[1] + c[2] + c[3];
    tmp[threadIdx.x] = tot;
    __syncthreads();
    int val = tot;
    for (int d = 1; d < 256; d <<= 1) {
        int add = (threadIdx.x >= d) ? tmp[threadIdx.x - d] : 0;
        __syncthreads();
        val += add;
        tmp[threadIdx.x] = val;
        __syncthreads();
    }
    int ex = val - tot;
    int e1 = ex + c[0], e2 = e1 + c[1], e3 = e2 + c[2];
    if (base + 0 < N_NODES) off[base + 0] = ex;
    if (base + 1 < N_NODES) off[base + 1] = e1;
    if (base + 2 < N_NODES) off[base + 2] = e2;
    if (base + 3 < N_NODES) off[base + 3] = e3;
    if (threadIdx.x == 255) bsum[blockIdx.x] = val;
}

__global__ void scan2(int* __restrict__ bsum) {
    if (threadIdx.x == 0 && blockIdx.x == 0) {
        int acc = 0;
        for (int i = 0; i < N_SCAN_BLKS; ++i) { int v = bsum[i]; bsum[i] = acc; acc += v; }
    }
}

__global__ void scan3(int* __restrict__ off, const int* __restrict__ bsum) {
    int i = blockIdx.x * blockDim.x + threadIdx.x;
    if (i < N_NODES) off[i] += bsum[i / SCAN_BLK];
    if (i == 0) off[N_NODES] = N_EDGES;
}

// ---------------- CSR fill ----------------

__global__ void fill_csr(const int* __restrict__ ei, const float* __restrict__ dinv,
                         const int* __restrict__ off, int* __restrict__ cursor,
                         EdgeRec* __restrict__ csr) {
    int e = blockIdx.x * blockDim.x + threadIdx.x;
    if (e >= N_EDGES) return;
    int s = ei[e], d = ei[N_EDGES + e];
    int pos = off[d] + atomicAdd(&cursor[d], 1);
    EdgeRec r; r.s = s; r.w = dinv[s] * dinv[d];
    csr[pos] = r;
}

// ---------------- dense transform: out = in @ W  (N x 128 @ 128 x 128), fp16 out ----------------

__device__ __forceinline__ float4 load4f(const float* p) { return *(const float4*)p; }
__device__ __forceinline__ float4 load4f(const _Float16* p) {
    h4 v = *(const h4*)p;
    return make_float4((float)v.x, (float)v.y, (float)v.z, (float)v.w);
}

template<typename TIN>
__global__ __launch_bounds__(256, 2) void gemm128(const TIN* __restrict__ in,
                                                  const float* __restrict__ W,
                                                  _Float16* __restrict__ out) {
    __shared__ float Wl[DIM][DIM];   // 64 KB
    __shared__ float Hl[32][DIM];    // 16 KB

    {
        const float4* W4 = (const float4*)W;
        float4* Wl4 = (float4*)&Wl[0][0];
        for (int i = threadIdx.x; i < DIM * DIM / 4; i += 256) Wl4[i] = W4[i];
    }

    const int c0 = (threadIdx.x & 31) * 4;
    const int r0 = (threadIdx.x >> 5) * 4;

    const int nchunks = N_NODES / 32;  // 3125
    for (int chunk = blockIdx.x; chunk < nchunks; chunk += gridDim.x) {
        const int row0 = chunk * 32;
        __syncthreads();
        {
            float4* Hl4 = (float4*)&Hl[0][0];
            const TIN* base = in + (size_t)row0 * DIM;
            for (int i = threadIdx.x; i < 32 * DIM / 4; i += 256) Hl4[i] = load4f(base + i * 4);
        }
        __syncthreads();

        float acc[4][4];
        #pragma unroll
        for (int r = 0; r < 4; ++r)
            #pragma unroll
            for (int c = 0; c < 4; ++c) acc[r][c] = 0.0f;

        #pragma unroll 4
        for (int k = 0; k < DIM; ++k) {
            const float4 w = *(const float4*)&Wl[k][c0];
            const float h0 = Hl[r0 + 0][k];
            const float h1 = Hl[r0 + 1][k];
            const float h2 = Hl[r0 + 2][k];
            const float h3 = Hl[r0 + 3][k];
            acc[0][0] += h0 * w.x; acc[0][1] += h0 * w.y; acc[0][2] += h0 * w.z; acc[0][3] += h0 * w.w;
            acc[1][0] += h1 * w.x; acc[1][1] += h1 * w.y; acc[1][2] += h1 * w.z; acc[1][3] += h1 * w.w;
            acc[2][0] += h2 * w.x; acc[2][1] += h2 * w.y; acc[2][2] += h2 * w.z; acc[2][3] += h2 * w.w;
            acc[3][0] += h3 * w.x; acc[3][1] += h3 * w.y; acc[3][2] += h3 * w.z; acc[3][3] += h3 * w.w;
        }

        #pragma unroll
        for (int r = 0; r < 4; ++r) {
            h4 v;
            v.x = (_Float16)acc[r][0]; v.y = (_Float16)acc[r][1];
            v.z = (_Float16)acc[r][2]; v.w = (_Float16)acc[r][3];
            *(h4*)&out[(size_t)(row0 + r0 + r) * DIM + c0] = v;
        }
    }
}

// ---------------- fused aggregate + bias + relu (+ pool on last layer) ----------------
// one wave64 per node; two 32-lane halves each process alternate edges;
// lane holds 4 dims (8B fp16) -> 256B coalesced row read per half-wave.

template<bool LAST>
__global__ __launch_bounds__(256) void gather_agg(const _Float16* __restrict__ hw,
                                                  const float* __restrict__ dinv,
                                                  const int* __restrict__ off,
                                                  const EdgeRec* __restrict__ csr,
                                                  const float* __restrict__ bias,
                                                  const int* __restrict__ batch,
                                                  _Float16* __restrict__ hout,
                                                  float* __restrict__ pooled) {
    const int i = (blockIdx.x * blockDim.x + threadIdx.x) >> 6;  // node = wave id
    if (i >= N_NODES) return;
    const int lane = threadIdx.x & 63;
    const int half = lane >> 5;   // which edge slot
    const int sub  = lane & 31;   // dim group: dims sub*4 .. sub*4+3
    const h4* hw4 = (const h4*)hw;  // row stride = 32 h4's

    const int beg = off[i], end = off[i + 1];
    float4 acc = make_float4(0.f, 0.f, 0.f, 0.f);

    int j;
    if (half == 0) {
        // self-loop message as item 0 of half 0
        float di = dinv[i];
        float w = di * di;
        h4 v = hw4[(size_t)i * 32 + sub];
        acc.x = w * (float)v.x; acc.y = w * (float)v.y;
        acc.z = w * (float)v.z; acc.w = w * (float)v.w;
        j = beg + 1;   // half 0 then takes csr items 1,3,5,...
    } else {
        j = beg;       // half 1 takes csr items 0,2,4,...
    }

    // 2x unroll per half: items j and j+2 (stride 4 covers both halves x unroll)
    for (; j + 2 < end; j += 4) {
        EdgeRec e0 = csr[j];
        EdgeRec e1 = csr[j + 2];
        h4 v0 = hw4[(size_t)e0.s * 32 + sub];
        h4 v1 = hw4[(size_t)e1.s * 32 + sub];
        acc.x += e0.w * (float)v0.x + e1.w * (float)v1.x;
        acc.y += e0.w * (float)v0.y + e1.w * (float)v1.y;
        acc.z += e0.w * (float)v0.z + e1.w * (float)v1.z;
        acc.w += e0.w * (float)v0.w + e1.w * (float)v1.w;
    }
    for (; j < end; j += 2) {
        EdgeRec e0 = csr[j];
        h4 v0 = hw4[(size_t)e0.s * 32 + sub];
        acc.x += e0.w * (float)v0.x;
        acc.y += e0.w * (float)v0.y;
        acc.z += e0.w * (float)v0.z;
        acc.w += e0.w * (float)v0.w;
    }

    // combine the two halves (lane l and l+32 hold the same dims)
    acc.x += __shfl_xor(acc.x, 32);
    acc.y += __shfl_xor(acc.y, 32);
    acc.z += __shfl_xor(acc.z, 32);
    acc.w += __shfl_xor(acc.w, 32);

    if (half == 0) {
        const float4 b = *(const float4*)&bias[sub * 4];
        acc.x = fmaxf(acc.x + b.x, 0.0f);
        acc.y = fmaxf(acc.y + b.y, 0.0f);
        acc.z = fmaxf(acc.z + b.z, 0.0f);
        acc.w = fmaxf(acc.w + b.w, 0.0f);
        if (!LAST) {
            h4 v;
            v.x = (_Float16)acc.x; v.y = (_Float16)acc.y;
            v.z = (_Float16)acc.z; v.w = (_Float16)acc.w;
            ((h4*)hout)[(size_t)i * 32 + sub] = v;
        } else {
            int g = batch[i];
            float* pp = &pooled[g * DIM + sub * 4];
            atomicAdd(pp + 0, acc.x);
            atomicAdd(pp + 1, acc.y);
            atomicAdd(pp + 2, acc.z);
            atomicAdd(pp + 3, acc.w);
        }
    }
}

// ---------------- head ----------------

__global__ void mlp_head(const float* __restrict__ pooled, const float* __restrict__ Wm,
                         const float* __restrict__ bm, float* __restrict__ out) {
    int t = blockIdx.x * blockDim.x + threadIdx.x;
    if (t >= N_GRAPHS * N_OUT) return;
    int b = t / N_OUT;
    int o = t % N_OUT;
    float acc = bm[o];
    #pragma unroll 8
    for (int k = 0; k < DIM; ++k) acc += pooled[b * DIM + k] * Wm[k * N_OUT + o];
    out[t] = acc;
}

// ---------------- launch ----------------

extern "C" void kernel_launch(void* const* d_in, const int* in_sizes, int n_in,
                              void* d_out, int out_size, void* d_ws, size_t ws_size,
                              hipStream_t stream) {
    const float* x     = (const float*)d_in[0];
    const int*   ei    = (const int*)d_in[1];
    const int*   batch = (const int*)d_in[2];
    const float* Ws    = (const float*)d_in[3];
    const float* bs    = (const float*)d_in[4];
    const float* Wm    = (const float*)d_in[5];
    const float* bm    = (const float*)d_in[6];
    float* out = (float*)d_out;

    // workspace carve-up (16B aligned regions)
    char* p = (char*)d_ws;
    int*      cnt     = (int*)p;        p += N_NODES * 4;
    float*    dinv    = (float*)p;      p += N_NODES * 4;
    int*      csr_off = (int*)p;        p += (N_NODES + 16) * 4;
    int*      cursor  = (int*)p;        p += N_NODES * 4;
    int*      bsum    = (int*)p;        p += 128 * 4;
    EdgeRec*  csr     = (EdgeRec*)p;    p += (size_t)N_EDGES * 8;
    _Float16* bufA    = (_Float16*)p;   p += (size_t)N_NODES * DIM * 2;  // hw
    _Float16* bufB    = (_Float16*)p;   p += (size_t)N_NODES * DIM * 2;  // h
    float*    pooled  = (float*)p;      p += N_GRAPHS * DIM * 4;

    const int nnode_blk = (N_NODES + 255) / 256;
    const int nedge_blk = (N_EDGES + 255) / 256;

    hipMemsetAsync(cnt, 0, N_NODES * 4, stream);
    hipMemsetAsync(cursor, 0, N_NODES * 4, stream);
    hipMemsetAsync(pooled, 0, N_GRAPHS * DIM * 4, stream);

    hist_dst<<<nedge_blk, 256, 0, stream>>>(ei, cnt);
    make_dinv<<<nnode_blk, 256, 0, stream>>>(cnt, dinv);

    scan1<<<N_SCAN_BLKS, 256, 0, stream>>>(cnt, csr_off, bsum);
    scan2<<<1, 64, 0, stream>>>(bsum);
    scan3<<<nnode_blk, 256, 0, stream>>>(csr_off, bsum);

    fill_csr<<<nedge_blk, 256, 0, stream>>>(ei, dinv, csr_off, cursor, csr);

    const int gather_grid = (N_NODES * 64 + 255) / 256;
    for (int l = 0; l < N_LAYERS; ++l) {
        if (l == 0) gemm128<float><<<1024, 256, 0, stream>>>(x, Ws, bufA);
        else        gemm128<_Float16><<<1024, 256, 0, stream>>>(bufB, Ws + (size_t)l * DIM * DIM, bufA);

        if (l < N_LAYERS - 1) {
            gather_agg<false><<<gather_grid, 256, 0, stream>>>(bufA, dinv, csr_off, csr,
                                                               bs + l * DIM, batch, bufB, pooled);
        } else {
            gather_agg<true><<<gather_grid, 256, 0, stream>>>(bufA, dinv, csr_off, csr,
                                                              bs + l * DIM, batch, nullptr, pooled);
        }
    }

    mlp_head<<<(N_GRAPHS * N_OUT + 255) / 256, 256, 0, stream>>>(pooled, Wm, bm, out);
}

// Round 4
// 464.101 us; speedup vs baseline: 1.6488x; 1.6488x over previous
//
#include <hip/hip_runtime.h>
#include <hip/hip_bf16.h>

#define N_NODES 100000
#define N_EDGES 640000
#define DIM 128
#define N_LAYERS 3
#define N_GRAPHS 128
#define N_OUT 10
#define SCAN_BLK 1024  // elements per scan block (256 thr x 4)
#define N_SCAN_BLKS ((N_NODES + SCAN_BLK - 1) / SCAN_BLK)  // 98

typedef _Float16 h4 __attribute__((ext_vector_type(4)));
typedef _Float16 h2 __attribute__((ext_vector_type(2)));

struct EdgeRec { int s; float w; };  // packed (src, norm-weight)

// ---------------- degree / norm ----------------

__global__ void hist_dst(const int* __restrict__ ei, int* __restrict__ cnt) {
    int e = blockIdx.x * blockDim.x + threadIdx.x;
    if (e < N_EDGES) atomicAdd(&cnt[ei[N_EDGES + e]], 1);
}

__global__ void make_dinv(const int* __restrict__ cnt, float* __restrict__ dinv) {
    int i = blockIdx.x * blockDim.x + threadIdx.x;
    if (i < N_NODES) dinv[i] = rsqrtf((float)(cnt[i] + 1));  // +1 self-loop
}

// ---------------- exclusive scan (3 kernels) ----------------

__global__ void scan1(const int* __restrict__ cnt, int* __restrict__ off, int* __restrict__ bsum) {
    __shared__ int tmp[256];
    int base = blockIdx.x * SCAN_BLK + threadIdx.x * 4;
    int c[4];
    #pragma unroll
    for (int k = 0; k < 4; ++k) c[k] = (base + k < N_NODES) ? cnt[base + k] : 0;
    int tot = c[0] + c[1] + c[2] + c[3];
    tmp[threadIdx.x] = tot;
    __syncthreads();
    int val = tot;
    for (int d = 1; d < 256; d <<= 1) {
        int add = (threadIdx.x >= d) ? tmp[threadIdx.x - d] : 0;
        __syncthreads();
        val += add;
        tmp[threadIdx.x] = val;
        __syncthreads();
    }
    int ex = val - tot;
    int e1 = ex + c[0], e2 = e1 + c[1], e3 = e2 + c[2];
    if (base + 0 < N_NODES) off[base + 0] = ex;
    if (base + 1 < N_NODES) off[base + 1] = e1;
    if (base + 2 < N_NODES) off[base + 2] = e2;
    if (base + 3 < N_NODES) off[base + 3] = e3;
    if (threadIdx.x == 255) bsum[blockIdx.x] = val;
}

__global__ void scan2(int* __restrict__ bsum) {
    if (threadIdx.x == 0 && blockIdx.x == 0) {
        int acc = 0;
        for (int i = 0; i < N_SCAN_BLKS; ++i) { int v = bsum[i]; bsum[i] = acc; acc += v; }
    }
}

__global__ void scan3(int* __restrict__ off, const int* __restrict__ bsum) {
    int i = blockIdx.x * blockDim.x + threadIdx.x;
    if (i < N_NODES) off[i] += bsum[i / SCAN_BLK];
    if (i == 0) off[N_NODES] = N_EDGES;
}

// ---------------- CSR fill ----------------

__global__ void fill_csr(const int* __restrict__ ei, const float* __restrict__ dinv,
                         const int* __restrict__ off, int* __restrict__ cursor,
                         EdgeRec* __restrict__ csr) {
    int e = blockIdx.x * blockDim.x + threadIdx.x;
    if (e >= N_EDGES) return;
    int s = ei[e], d = ei[N_EDGES + e];
    int pos = off[d] + atomicAdd(&cursor[d], 1);
    EdgeRec r; r.s = s; r.w = dinv[s] * dinv[d];
    csr[pos] = r;
}

// ---------------- graph bounds (batch is sorted) ----------------

__global__ void init_bounds(int* __restrict__ gs, int* __restrict__ ge) {
    int g = blockIdx.x * blockDim.x + threadIdx.x;
    if (g < N_GRAPHS) { gs[g] = N_NODES; ge[g] = -1; }
}

__global__ void find_bounds(const int* __restrict__ batch, int* __restrict__ gs, int* __restrict__ ge) {
    int i = blockIdx.x * blockDim.x + threadIdx.x;
    if (i >= N_NODES) return;
    int b = batch[i];
    // only boundary nodes need atomics
    if (i == 0 || batch[i - 1] != b) atomicMin(&gs[b], i);
    if (i == N_NODES - 1 || batch[i + 1] != b) atomicMax(&ge[b], i);
}

// ---------------- dense transform: out = in @ W  (N x 128 @ 128 x 128), fp16 out ----------------

__device__ __forceinline__ float4 load4f(const float* p) { return *(const float4*)p; }
__device__ __forceinline__ float4 load4f(const _Float16* p) {
    h4 v = *(const h4*)p;
    return make_float4((float)v.x, (float)v.y, (float)v.z, (float)v.w);
}

template<typename TIN>
__global__ __launch_bounds__(256, 2) void gemm128(const TIN* __restrict__ in,
                                                  const float* __restrict__ W,
                                                  _Float16* __restrict__ out) {
    __shared__ float Wl[DIM][DIM];   // 64 KB
    __shared__ float Hl[32][DIM];    // 16 KB

    {
        const float4* W4 = (const float4*)W;
        float4* Wl4 = (float4*)&Wl[0][0];
        for (int i = threadIdx.x; i < DIM * DIM / 4; i += 256) Wl4[i] = W4[i];
    }

    const int c0 = (threadIdx.x & 31) * 4;
    const int r0 = (threadIdx.x >> 5) * 4;

    const int nchunks = N_NODES / 32;  // 3125
    for (int chunk = blockIdx.x; chunk < nchunks; chunk += gridDim.x) {
        const int row0 = chunk * 32;
        __syncthreads();
        {
            float4* Hl4 = (float4*)&Hl[0][0];
            const TIN* base = in + (size_t)row0 * DIM;
            for (int i = threadIdx.x; i < 32 * DIM / 4; i += 256) Hl4[i] = load4f(base + i * 4);
        }
        __syncthreads();

        float acc[4][4];
        #pragma unroll
        for (int r = 0; r < 4; ++r)
            #pragma unroll
            for (int c = 0; c < 4; ++c) acc[r][c] = 0.0f;

        #pragma unroll 4
        for (int k = 0; k < DIM; ++k) {
            const float4 w = *(const float4*)&Wl[k][c0];
            const float h0 = Hl[r0 + 0][k];
            const float h1 = Hl[r0 + 1][k];
            const float h2_ = Hl[r0 + 2][k];
            const float h3_ = Hl[r0 + 3][k];
            acc[0][0] += h0 * w.x;  acc[0][1] += h0 * w.y;  acc[0][2] += h0 * w.z;  acc[0][3] += h0 * w.w;
            acc[1][0] += h1 * w.x;  acc[1][1] += h1 * w.y;  acc[1][2] += h1 * w.z;  acc[1][3] += h1 * w.w;
            acc[2][0] += h2_ * w.x; acc[2][1] += h2_ * w.y; acc[2][2] += h2_ * w.z; acc[2][3] += h2_ * w.w;
            acc[3][0] += h3_ * w.x; acc[3][1] += h3_ * w.y; acc[3][2] += h3_ * w.z; acc[3][3] += h3_ * w.w;
        }

        #pragma unroll
        for (int r = 0; r < 4; ++r) {
            h4 v;
            v.x = (_Float16)acc[r][0]; v.y = (_Float16)acc[r][1];
            v.z = (_Float16)acc[r][2]; v.w = (_Float16)acc[r][3];
            *(h4*)&out[(size_t)(row0 + r0 + r) * DIM + c0] = v;
        }
    }
}

// ---------------- fused aggregate + bias + relu ----------------
// one wave64 per node; two 32-lane halves each process alternate edges;
// lane holds 4 dims (8B fp16) -> 256B coalesced row read per half-wave.

__global__ __launch_bounds__(256) void gather_agg(const _Float16* __restrict__ hw,
                                                  const float* __restrict__ dinv,
                                                  const int* __restrict__ off,
                                                  const EdgeRec* __restrict__ csr,
                                                  const float* __restrict__ bias,
                                                  _Float16* __restrict__ hout) {
    const int i = (blockIdx.x * blockDim.x + threadIdx.x) >> 6;  // node = wave id
    if (i >= N_NODES) return;
    const int lane = threadIdx.x & 63;
    const int half = lane >> 5;   // which edge slot
    const int sub  = lane & 31;   // dim group: dims sub*4 .. sub*4+3
    const h4* hw4 = (const h4*)hw;  // row stride = 32 h4's

    const int beg = off[i], end = off[i + 1];
    float4 acc = make_float4(0.f, 0.f, 0.f, 0.f);

    int j;
    if (half == 0) {
        // self-loop message as item 0 of half 0
        float di = dinv[i];
        float w = di * di;
        h4 v = hw4[(size_t)i * 32 + sub];
        acc.x = w * (float)v.x; acc.y = w * (float)v.y;
        acc.z = w * (float)v.z; acc.w = w * (float)v.w;
        j = beg + 1;   // half 0 then takes csr items 1,3,5,...
    } else {
        j = beg;       // half 1 takes csr items 0,2,4,...
    }

    for (; j + 2 < end; j += 4) {
        EdgeRec e0 = csr[j];
        EdgeRec e1 = csr[j + 2];
        h4 v0 = hw4[(size_t)e0.s * 32 + sub];
        h4 v1 = hw4[(size_t)e1.s * 32 + sub];
        acc.x += e0.w * (float)v0.x + e1.w * (float)v1.x;
        acc.y += e0.w * (float)v0.y + e1.w * (float)v1.y;
        acc.z += e0.w * (float)v0.z + e1.w * (float)v1.z;
        acc.w += e0.w * (float)v0.w + e1.w * (float)v1.w;
    }
    for (; j < end; j += 2) {
        EdgeRec e0 = csr[j];
        h4 v0 = hw4[(size_t)e0.s * 32 + sub];
        acc.x += e0.w * (float)v0.x;
        acc.y += e0.w * (float)v0.y;
        acc.z += e0.w * (float)v0.z;
        acc.w += e0.w * (float)v0.w;
    }

    // combine the two halves (lane l and l+32 hold the same dims)
    acc.x += __shfl_xor(acc.x, 32);
    acc.y += __shfl_xor(acc.y, 32);
    acc.z += __shfl_xor(acc.z, 32);
    acc.w += __shfl_xor(acc.w, 32);

    if (half == 0) {
        const float4 b = *(const float4*)&bias[sub * 4];
        h4 v;
        v.x = (_Float16)fmaxf(acc.x + b.x, 0.0f);
        v.y = (_Float16)fmaxf(acc.y + b.y, 0.0f);
        v.z = (_Float16)fmaxf(acc.z + b.z, 0.0f);
        v.w = (_Float16)fmaxf(acc.w + b.w, 0.0f);
        ((h4*)hout)[(size_t)i * 32 + sub] = v;
    }
}

// ---------------- segmented pool (batch sorted -> contiguous ranges) ----------------
// one block per graph: 4 row-groups x 64 dim-lanes (h2 per lane)

__global__ __launch_bounds__(256) void pool_seg(const _Float16* __restrict__ h,
                                                const int* __restrict__ gs,
                                                const int* __restrict__ ge,
                                                float* __restrict__ pooled) {
    const int g = blockIdx.x;
    const int t = threadIdx.x;
    const int d = t & 63;        // h2 index (dims d*2, d*2+1)
    const int rgrp = t >> 6;     // 0..3
    const int start = gs[g];
    const int endi = ge[g] + 1;  // empty graph: start=N, endi=0 -> no iterations

    const h2* h2p = (const h2*)h;  // row stride 64
    float ax = 0.f, ay = 0.f;
    for (int r = start + rgrp; r < endi; r += 4) {
        h2 v = h2p[(size_t)r * 64 + d];
        ax += (float)v.x; ay += (float)v.y;
    }

    __shared__ float red[4][DIM];
    red[rgrp][d * 2 + 0] = ax;
    red[rgrp][d * 2 + 1] = ay;
    __syncthreads();
    if (t < DIM) {
        pooled[g * DIM + t] = red[0][t] + red[1][t] + red[2][t] + red[3][t];
    }
}

// ---------------- head ----------------

__global__ void mlp_head(const float* __restrict__ pooled, const float* __restrict__ Wm,
                         const float* __restrict__ bm, float* __restrict__ out) {
    int t = blockIdx.x * blockDim.x + threadIdx.x;
    if (t >= N_GRAPHS * N_OUT) return;
    int b = t / N_OUT;
    int o = t % N_OUT;
    float acc = bm[o];
    #pragma unroll 8
    for (int k = 0; k < DIM; ++k) acc += pooled[b * DIM + k] * Wm[k * N_OUT + o];
    out[t] = acc;
}

// ---------------- launch ----------------

extern "C" void kernel_launch(void* const* d_in, const int* in_sizes, int n_in,
                              void* d_out, int out_size, void* d_ws, size_t ws_size,
                              hipStream_t stream) {
    const float* x     = (const float*)d_in[0];
    const int*   ei    = (const int*)d_in[1];
    const int*   batch = (const int*)d_in[2];
    const float* Ws    = (const float*)d_in[3];
    const float* bs    = (const float*)d_in[4];
    const float* Wm    = (const float*)d_in[5];
    const float* bm    = (const float*)d_in[6];
    float* out = (float*)d_out;

    // workspace carve-up (16B aligned regions)
    char* p = (char*)d_ws;
    int*      cnt     = (int*)p;        p += N_NODES * 4;
    float*    dinv    = (float*)p;      p += N_NODES * 4;
    int*      csr_off = (int*)p;        p += (N_NODES + 16) * 4;
    int*      cursor  = (int*)p;        p += N_NODES * 4;
    int*      bsum    = (int*)p;        p += 128 * 4;
    int*      gs      = (int*)p;        p += N_GRAPHS * 4;
    int*      ge      = (int*)p;        p += N_GRAPHS * 4;
    EdgeRec*  csr     = (EdgeRec*)p;    p += (size_t)N_EDGES * 8;
    _Float16* bufA    = (_Float16*)p;   p += (size_t)N_NODES * DIM * 2;  // hw
    _Float16* bufB    = (_Float16*)p;   p += (size_t)N_NODES * DIM * 2;  // h
    float*    pooled  = (float*)p;      p += N_GRAPHS * DIM * 4;

    const int nnode_blk = (N_NODES + 255) / 256;
    const int nedge_blk = (N_EDGES + 255) / 256;

    hipMemsetAsync(cnt, 0, N_NODES * 4, stream);
    hipMemsetAsync(cursor, 0, N_NODES * 4, stream);

    hist_dst<<<nedge_blk, 256, 0, stream>>>(ei, cnt);
    make_dinv<<<nnode_blk, 256, 0, stream>>>(cnt, dinv);

    scan1<<<N_SCAN_BLKS, 256, 0, stream>>>(cnt, csr_off, bsum);
    scan2<<<1, 64, 0, stream>>>(bsum);
    scan3<<<nnode_blk, 256, 0, stream>>>(csr_off, bsum);

    fill_csr<<<nedge_blk, 256, 0, stream>>>(ei, dinv, csr_off, cursor, csr);

    init_bounds<<<1, 256, 0, stream>>>(gs, ge);
    find_bounds<<<nnode_blk, 256, 0, stream>>>(batch, gs, ge);

    const int gather_grid = (N_NODES * 64 + 255) / 256;
    for (int l = 0; l < N_LAYERS; ++l) {
        if (l == 0) gemm128<float><<<1024, 256, 0, stream>>>(x, Ws, bufA);
        else        gemm128<_Float16><<<1024, 256, 0, stream>>>(bufB, Ws + (size_t)l * DIM * DIM, bufA);
        gather_agg<<<gather_grid, 256, 0, stream>>>(bufA, dinv, csr_off, csr, bs + l * DIM, bufB);
    }

    pool_seg<<<N_GRAPHS, 256, 0, stream>>>(bufB, gs, ge, pooled);
    mlp_head<<<(N_GRAPHS * N_OUT + 255) / 256, 256, 0, stream>>>(pooled, Wm, bm, out);
}

// Round 5
// 335.121 us; speedup vs baseline: 2.2834x; 1.3849x over previous
//
#include <hip/hip_runtime.h>
#include <hip/hip_bf16.h>

#define N_NODES 100000
#define N_EDGES 640000
#define DIM 128
#define N_LAYERS 3
#define N_GRAPHS 128
#define N_OUT 10
#define SCAN_BLK 1024  // elements per scan block (256 thr x 4)
#define N_SCAN_BLKS ((N_NODES + SCAN_BLK - 1) / SCAN_BLK)  // 98

typedef _Float16 h4 __attribute__((ext_vector_type(4)));
typedef _Float16 h2 __attribute__((ext_vector_type(2)));
typedef _Float16 h8 __attribute__((ext_vector_type(8)));
typedef float f32x4 __attribute__((ext_vector_type(4)));

struct EdgeRec { int s; float w; };  // packed (src, norm-weight)

// ---------------- degree / norm ----------------

__global__ void hist_dst(const int* __restrict__ ei, int* __restrict__ cnt) {
    int e = blockIdx.x * blockDim.x + threadIdx.x;
    if (e < N_EDGES) atomicAdd(&cnt[ei[N_EDGES + e]], 1);
}

__global__ void make_dinv(const int* __restrict__ cnt, float* __restrict__ dinv) {
    int i = blockIdx.x * blockDim.x + threadIdx.x;
    if (i < N_NODES) dinv[i] = rsqrtf((float)(cnt[i] + 1));  // +1 self-loop
}

// ---------------- exclusive scan (3 kernels) ----------------

__global__ void scan1(const int* __restrict__ cnt, int* __restrict__ off, int* __restrict__ bsum) {
    __shared__ int tmp[256];
    int base = blockIdx.x * SCAN_BLK + threadIdx.x * 4;
    int c[4];
    #pragma unroll
    for (int k = 0; k < 4; ++k) c[k] = (base + k < N_NODES) ? cnt[base + k] : 0;
    int tot = c[0] + c[1] + c[2] + c[3];
    tmp[threadIdx.x] = tot;
    __syncthreads();
    int val = tot;
    for (int d = 1; d < 256; d <<= 1) {
        int add = (threadIdx.x >= d) ? tmp[threadIdx.x - d] : 0;
        __syncthreads();
        val += add;
        tmp[threadIdx.x] = val;
        __syncthreads();
    }
    int ex = val - tot;
    int e1 = ex + c[0], e2 = e1 + c[1], e3 = e2 + c[2];
    if (base + 0 < N_NODES) off[base + 0] = ex;
    if (base + 1 < N_NODES) off[base + 1] = e1;
    if (base + 2 < N_NODES) off[base + 2] = e2;
    if (base + 3 < N_NODES) off[base + 3] = e3;
    if (threadIdx.x == 255) bsum[blockIdx.x] = val;
}

__global__ void scan2(int* __restrict__ bsum) {
    if (threadIdx.x == 0 && blockIdx.x == 0) {
        int acc = 0;
        for (int i = 0; i < N_SCAN_BLKS; ++i) { int v = bsum[i]; bsum[i] = acc; acc += v; }
    }
}

__global__ void scan3(int* __restrict__ off, const int* __restrict__ bsum) {
    int i = blockIdx.x * blockDim.x + threadIdx.x;
    if (i < N_NODES) off[i] += bsum[i / SCAN_BLK];
    if (i == 0) off[N_NODES] = N_EDGES;
}

// ---------------- CSR fill ----------------

__global__ void fill_csr(const int* __restrict__ ei, const float* __restrict__ dinv,
                         const int* __restrict__ off, int* __restrict__ cursor,
                         EdgeRec* __restrict__ csr) {
    int e = blockIdx.x * blockDim.x + threadIdx.x;
    if (e >= N_EDGES) return;
    int s = ei[e], d = ei[N_EDGES + e];
    int pos = off[d] + atomicAdd(&cursor[d], 1);
    EdgeRec r; r.s = s; r.w = dinv[s] * dinv[d];
    csr[pos] = r;
}

// ---------------- graph bounds (batch is sorted) ----------------

__global__ void init_bounds(int* __restrict__ gs, int* __restrict__ ge) {
    int g = blockIdx.x * blockDim.x + threadIdx.x;
    if (g < N_GRAPHS) { gs[g] = N_NODES; ge[g] = -1; }
}

__global__ void find_bounds(const int* __restrict__ batch, int* __restrict__ gs, int* __restrict__ ge) {
    int i = blockIdx.x * blockDim.x + threadIdx.x;
    if (i >= N_NODES) return;
    int b = batch[i];
    if (i == 0 || batch[i - 1] != b) atomicMin(&gs[b], i);
    if (i == N_NODES - 1 || batch[i + 1] != b) atomicMax(&ge[b], i);
}

// ---------------- W prep: transpose + fp16 + XOR-swizzle ----------------
// Wt_swz[l][n][u'] (u' = 8B unit) where u' = u ^ (n&31), unit u holds W[u*4..u*4+3][n].
// Swizzle makes the per-16-lane-group ds_read_b64 in the GEMM hit all 32 banks.

__global__ void wt_prep(const float* __restrict__ Ws, _Float16* __restrict__ wt) {
    int t = blockIdx.x * blockDim.x + threadIdx.x;  // (l, n, u): 3*128*32
    if (t >= N_LAYERS * DIM * 32) return;
    int u = t & 31;
    int n = (t >> 5) & 127;
    int l = t >> 12;
    const float* W = Ws + (size_t)l * DIM * DIM;
    int k0 = u * 4;
    h4 v;
    v.x = (_Float16)W[(k0 + 0) * DIM + n];
    v.y = (_Float16)W[(k0 + 1) * DIM + n];
    v.z = (_Float16)W[(k0 + 2) * DIM + n];
    v.w = (_Float16)W[(k0 + 3) * DIM + n];
    int du = u ^ (n & 31);
    ((h4*)wt)[(size_t)l * 4096 + n * 32 + du] = v;
}

// ---------------- MFMA dense transform: out = in @ W  (fp16 out, f32 acc) ----------------
// A = Wt (n-major rows), B = h rows => D[i=n][j=m]; lane's 4 D-regs are 4 contiguous
// output columns -> single 8B fp16 store per tile. No barrier in the K-loop.

__device__ __forceinline__ h4 loadfrag(const _Float16* p) { return *(const h4*)p; }
__device__ __forceinline__ h4 loadfrag(const float* p) {
    float4 f = *(const float4*)p;
    h4 v; v.x = (_Float16)f.x; v.y = (_Float16)f.y; v.z = (_Float16)f.z; v.w = (_Float16)f.w;
    return v;
}

template<typename TIN>
__global__ __launch_bounds__(256) void gemm_mfma(const TIN* __restrict__ in,
                                                 const _Float16* __restrict__ wt,
                                                 _Float16* __restrict__ out) {
    __shared__ h4 Wl[4096];  // 32 KB swizzled W^T
    {
        const float4* src = (const float4*)wt;
        float4* dst = (float4*)Wl;
        #pragma unroll
        for (int i = 0; i < 8; ++i) dst[threadIdx.x + i * 256] = src[threadIdx.x + i * 256];
    }
    __syncthreads();

    const int wave = threadIdx.x >> 6;
    const int lane = threadIdx.x & 63;
    const int m0 = blockIdx.x * 64 + wave * 16;
    if (m0 >= N_NODES) return;   // N_NODES % 16 == 0: waves are all-valid or all-OOB

    const int row = lane & 15;   // m-offset (B col) / n-offset (A row)
    const int g   = lane >> 4;   // k-group
    const int m   = m0 + row;
    const TIN* arow = in + (size_t)m * DIM;

    f32x4 acc[8] = {};  // 8 n-tiles of 16 cols

    #pragma unroll
    for (int kc = 0; kc < 8; ++kc) {
        const int k = kc * 16 + g * 4;
        const h4 bfrag = loadfrag(arow + k);        // B[k..k+3][m]
        const int u = kc * 4 + g;
        #pragma unroll
        for (int nb = 0; nb < 8; ++nb) {
            const int n = nb * 16 + row;
            const h4 afrag = Wl[n * 32 + (u ^ (n & 31))];  // A[n][k..k+3]
            acc[nb] = __builtin_amdgcn_mfma_f32_16x16x16f16(afrag, bfrag, acc[nb], 0, 0, 0);
        }
    }

    _Float16* orow = out + (size_t)m * DIM;
    #pragma unroll
    for (int nb = 0; nb < 8; ++nb) {
        h4 v;
        v.x = (_Float16)acc[nb].x; v.y = (_Float16)acc[nb].y;
        v.z = (_Float16)acc[nb].z; v.w = (_Float16)acc[nb].w;
        ((h4*)orow)[nb * 4 + g] = v;   // cols nb*16 + g*4 .. +3
    }
}

// ---------------- fused aggregate + bias + relu ----------------
// one wave64 per node; four 16-lane quarters stream alternate edges (2x unrolled
// -> 8 row-gathers in flight); lane holds 8 dims (16B) -> 256B coalesced row per quarter.

__global__ __launch_bounds__(256) void gather_agg(const _Float16* __restrict__ hw,
                                                  const float* __restrict__ dinv,
                                                  const int* __restrict__ off,
                                                  const EdgeRec* __restrict__ csr,
                                                  const float* __restrict__ bias,
                                                  _Float16* __restrict__ hout) {
    const int i = (blockIdx.x * blockDim.x + threadIdx.x) >> 6;  // node = wave id
    if (i >= N_NODES) return;
    const int lane = threadIdx.x & 63;
    const int q   = lane >> 4;   // edge stream 0..3
    const int sub = lane & 15;   // dims sub*8 .. sub*8+7
    const h8* hw8 = (const h8*)hw;  // row stride = 16 h8 units

    const int beg = off[i], end = off[i + 1];
    float accf[8] = {0.f, 0.f, 0.f, 0.f, 0.f, 0.f, 0.f, 0.f};

    if (q == 3) {  // self-loop message handled by stream 3
        float di = dinv[i];
        float w = di * di;
        h8 v = hw8[(size_t)i * 16 + sub];
        #pragma unroll
        for (int d = 0; d < 8; ++d) accf[d] = w * (float)v[d];
    }

    int j = beg + q;
    for (; j + 4 < end; j += 8) {
        EdgeRec e0 = csr[j];
        EdgeRec e1 = csr[j + 4];
        h8 v0 = hw8[(size_t)e0.s * 16 + sub];
        h8 v1 = hw8[(size_t)e1.s * 16 + sub];
        #pragma unroll
        for (int d = 0; d < 8; ++d) accf[d] += e0.w * (float)v0[d] + e1.w * (float)v1[d];
    }
    for (; j < end; j += 4) {
        EdgeRec e0 = csr[j];
        h8 v0 = hw8[(size_t)e0.s * 16 + sub];
        #pragma unroll
        for (int d = 0; d < 8; ++d) accf[d] += e0.w * (float)v0[d];
    }

    // reduce across the 4 quarters
    #pragma unroll
    for (int d = 0; d < 8; ++d) {
        float a = accf[d];
        a += __shfl_xor(a, 16);
        a += __shfl_xor(a, 32);
        accf[d] = a;
    }

    if (q == 0) {
        const float4 b0 = *(const float4*)&bias[sub * 8];
        const float4 b1 = *(const float4*)&bias[sub * 8 + 4];
        h8 v;
        v[0] = (_Float16)fmaxf(accf[0] + b0.x, 0.0f);
        v[1] = (_Float16)fmaxf(accf[1] + b0.y, 0.0f);
        v[2] = (_Float16)fmaxf(accf[2] + b0.z, 0.0f);
        v[3] = (_Float16)fmaxf(accf[3] + b0.w, 0.0f);
        v[4] = (_Float16)fmaxf(accf[4] + b1.x, 0.0f);
        v[5] = (_Float16)fmaxf(accf[5] + b1.y, 0.0f);
        v[6] = (_Float16)fmaxf(accf[6] + b1.z, 0.0f);
        v[7] = (_Float16)fmaxf(accf[7] + b1.w, 0.0f);
        ((h8*)hout)[(size_t)i * 16 + sub] = v;
    }
}

// ---------------- segmented pool (batch sorted -> contiguous ranges) ----------------

__global__ __launch_bounds__(256) void pool_seg(const _Float16* __restrict__ h,
                                                const int* __restrict__ gs,
                                                const int* __restrict__ ge,
                                                float* __restrict__ pooled) {
    const int g = blockIdx.x;
    const int t = threadIdx.x;
    const int d = t & 63;        // h2 index (dims d*2, d*2+1)
    const int rgrp = t >> 6;     // 0..3
    const int start = gs[g];
    const int endi = ge[g] + 1;

    const h2* h2p = (const h2*)h;  // row stride 64
    float ax = 0.f, ay = 0.f;
    for (int r = start + rgrp; r < endi; r += 4) {
        h2 v = h2p[(size_t)r * 64 + d];
        ax += (float)v.x; ay += (float)v.y;
    }

    __shared__ float red[4][DIM];
    red[rgrp][d * 2 + 0] = ax;
    red[rgrp][d * 2 + 1] = ay;
    __syncthreads();
    if (t < DIM) {
        pooled[g * DIM + t] = red[0][t] + red[1][t] + red[2][t] + red[3][t];
    }
}

// ---------------- head ----------------

__global__ void mlp_head(const float* __restrict__ pooled, const float* __restrict__ Wm,
                         const float* __restrict__ bm, float* __restrict__ out) {
    int t = blockIdx.x * blockDim.x + threadIdx.x;
    if (t >= N_GRAPHS * N_OUT) return;
    int b = t / N_OUT;
    int o = t % N_OUT;
    float acc = bm[o];
    #pragma unroll 8
    for (int k = 0; k < DIM; ++k) acc += pooled[b * DIM + k] * Wm[k * N_OUT + o];
    out[t] = acc;
}

// ---------------- launch ----------------

extern "C" void kernel_launch(void* const* d_in, const int* in_sizes, int n_in,
                              void* d_out, int out_size, void* d_ws, size_t ws_size,
                              hipStream_t stream) {
    const float* x     = (const float*)d_in[0];
    const int*   ei    = (const int*)d_in[1];
    const int*   batch = (const int*)d_in[2];
    const float* Ws    = (const float*)d_in[3];
    const float* bs    = (const float*)d_in[4];
    const float* Wm    = (const float*)d_in[5];
    const float* bm    = (const float*)d_in[6];
    float* out = (float*)d_out;

    // workspace carve-up (16B aligned regions; cnt+cursor adjacent for one memset)
    char* p = (char*)d_ws;
    int*      cnt     = (int*)p;        p += N_NODES * 4;
    int*      cursor  = (int*)p;        p += N_NODES * 4;
    float*    dinv    = (float*)p;      p += N_NODES * 4;
    int*      csr_off = (int*)p;        p += (N_NODES + 16) * 4;
    int*      bsum    = (int*)p;        p += 128 * 4;
    int*      gs      = (int*)p;        p += N_GRAPHS * 4;
    int*      ge      = (int*)p;        p += N_GRAPHS * 4;
    _Float16* wt      = (_Float16*)p;   p += (size_t)N_LAYERS * DIM * DIM * 2;  // swizzled W^T fp16
    EdgeRec*  csr     = (EdgeRec*)p;    p += (size_t)N_EDGES * 8;
    _Float16* bufA    = (_Float16*)p;   p += (size_t)N_NODES * DIM * 2;  // hw
    _Float16* bufB    = (_Float16*)p;   p += (size_t)N_NODES * DIM * 2;  // h
    float*    pooled  = (float*)p;      p += N_GRAPHS * DIM * 4;

    const int nnode_blk = (N_NODES + 255) / 256;
    const int nedge_blk = (N_EDGES + 255) / 256;

    hipMemsetAsync(cnt, 0, N_NODES * 8, stream);  // cnt + cursor

    hist_dst<<<nedge_blk, 256, 0, stream>>>(ei, cnt);
    make_dinv<<<nnode_blk, 256, 0, stream>>>(cnt, dinv);
    wt_prep<<<(N_LAYERS * DIM * 32 + 255) / 256, 256, 0, stream>>>(Ws, wt);

    scan1<<<N_SCAN_BLKS, 256, 0, stream>>>(cnt, csr_off, bsum);
    scan2<<<1, 64, 0, stream>>>(bsum);
    scan3<<<nnode_blk, 256, 0, stream>>>(csr_off, bsum);

    fill_csr<<<nedge_blk, 256, 0, stream>>>(ei, dinv, csr_off, cursor, csr);

    init_bounds<<<1, 256, 0, stream>>>(gs, ge);
    find_bounds<<<nnode_blk, 256, 0, stream>>>(batch, gs, ge);

    const int gemm_grid = (N_NODES + 63) / 64;           // 1563 (last block wave-guarded)
    const int gather_grid = (N_NODES * 64 + 255) / 256;  // one wave per node
    for (int l = 0; l < N_LAYERS; ++l) {
        if (l == 0) gemm_mfma<float><<<gemm_grid, 256, 0, stream>>>(x, wt, bufA);
        else        gemm_mfma<_Float16><<<gemm_grid, 256, 0, stream>>>(bufB, wt + (size_t)l * DIM * DIM, bufA);
        gather_agg<<<gather_grid, 256, 0, stream>>>(bufA, dinv, csr_off, csr, bs + l * DIM, bufB);
    }

    pool_seg<<<N_GRAPHS, 256, 0, stream>>>(bufB, gs, ge, pooled);
    mlp_head<<<(N_GRAPHS * N_OUT + 255) / 256, 256, 0, stream>>>(pooled, Wm, bm, out);
}

// Round 6
// 299.575 us; speedup vs baseline: 2.5543x; 1.1187x over previous
//
#include <hip/hip_runtime.h>
#include <hip/hip_bf16.h>

#define N_NODES 100000
#define N_EDGES 640000
#define DIM 128
#define N_LAYERS 3
#define N_GRAPHS 128
#define N_OUT 10
#define SCAN_BLK 1024  // elements per scan block (256 thr x 4)
#define N_SCAN_BLKS ((N_NODES + SCAN_BLK - 1) / SCAN_BLK)  // 98
#define PCHUNK 128     // rows per pool block

typedef _Float16 h4 __attribute__((ext_vector_type(4)));
typedef _Float16 h2 __attribute__((ext_vector_type(2)));
typedef _Float16 h8 __attribute__((ext_vector_type(8)));
typedef float f32x4 __attribute__((ext_vector_type(4)));

struct EdgeRec { int s; float w; };  // packed (src, norm-weight)

// ---------------- degree / norm ----------------

__global__ void hist_dst(const int* __restrict__ ei, int* __restrict__ cnt) {
    int e = blockIdx.x * blockDim.x + threadIdx.x;
    if (e < N_EDGES) atomicAdd(&cnt[ei[N_EDGES + e]], 1);
}

__global__ void make_dinv(const int* __restrict__ cnt, float* __restrict__ dinv) {
    int i = blockIdx.x * blockDim.x + threadIdx.x;
    if (i < N_NODES) dinv[i] = rsqrtf((float)(cnt[i] + 1));  // +1 self-loop
}

// ---------------- exclusive scan (3 kernels) ----------------

__global__ void scan1(const int* __restrict__ cnt, int* __restrict__ off, int* __restrict__ bsum) {
    __shared__ int tmp[256];
    int base = blockIdx.x * SCAN_BLK + threadIdx.x * 4;
    int c[4];
    #pragma unroll
    for (int k = 0; k < 4; ++k) c[k] = (base + k < N_NODES) ? cnt[base + k] : 0;
    int tot = c[0] + c[1] + c[2] + c[3];
    tmp[threadIdx.x] = tot;
    __syncthreads();
    int val = tot;
    for (int d = 1; d < 256; d <<= 1) {
        int add = (threadIdx.x >= d) ? tmp[threadIdx.x - d] : 0;
        __syncthreads();
        val += add;
        tmp[threadIdx.x] = val;
        __syncthreads();
    }
    int ex = val - tot;
    int e1 = ex + c[0], e2 = e1 + c[1], e3 = e2 + c[2];
    if (base + 0 < N_NODES) off[base + 0] = ex;
    if (base + 1 < N_NODES) off[base + 1] = e1;
    if (base + 2 < N_NODES) off[base + 2] = e2;
    if (base + 3 < N_NODES) off[base + 3] = e3;
    if (threadIdx.x == 255) bsum[blockIdx.x] = val;
}

__global__ void scan2(int* __restrict__ bsum) {
    if (threadIdx.x == 0 && blockIdx.x == 0) {
        int acc = 0;
        for (int i = 0; i < N_SCAN_BLKS; ++i) { int v = bsum[i]; bsum[i] = acc; acc += v; }
    }
}

__global__ void scan3(int* __restrict__ off, const int* __restrict__ bsum) {
    int i = blockIdx.x * blockDim.x + threadIdx.x;
    if (i < N_NODES) off[i] += bsum[i / SCAN_BLK];
    if (i == 0) off[N_NODES] = N_EDGES;
}

// ---------------- CSR fill ----------------

__global__ void fill_csr(const int* __restrict__ ei, const float* __restrict__ dinv,
                         const int* __restrict__ off, int* __restrict__ cursor,
                         EdgeRec* __restrict__ csr) {
    int e = blockIdx.x * blockDim.x + threadIdx.x;
    if (e >= N_EDGES) return;
    int s = ei[e], d = ei[N_EDGES + e];
    int pos = off[d] + atomicAdd(&cursor[d], 1);
    EdgeRec r; r.s = s; r.w = dinv[s] * dinv[d];
    csr[pos] = r;
}

// ---------------- W prep: transpose + fp16 + XOR-swizzle ----------------
// Wt_swz[l][n][u'] (u' = 8B unit) where u' = u ^ (n&31), unit u holds W[u*4..u*4+3][n].

__global__ void wt_prep(const float* __restrict__ Ws, _Float16* __restrict__ wt) {
    int t = blockIdx.x * blockDim.x + threadIdx.x;  // (l, n, u): 3*128*32
    if (t >= N_LAYERS * DIM * 32) return;
    int u = t & 31;
    int n = (t >> 5) & 127;
    int l = t >> 12;
    const float* W = Ws + (size_t)l * DIM * DIM;
    int k0 = u * 4;
    h4 v;
    v.x = (_Float16)W[(k0 + 0) * DIM + n];
    v.y = (_Float16)W[(k0 + 1) * DIM + n];
    v.z = (_Float16)W[(k0 + 2) * DIM + n];
    v.w = (_Float16)W[(k0 + 3) * DIM + n];
    int du = u ^ (n & 31);
    ((h4*)wt)[(size_t)l * 4096 + n * 32 + du] = v;
}

// ---------------- MFMA dense transform: out = in @ W  (fp16 out, f32 acc) ----------------

__device__ __forceinline__ h4 loadfrag(const _Float16* p) { return *(const h4*)p; }
__device__ __forceinline__ h4 loadfrag(const float* p) {
    float4 f = *(const float4*)p;
    h4 v; v.x = (_Float16)f.x; v.y = (_Float16)f.y; v.z = (_Float16)f.z; v.w = (_Float16)f.w;
    return v;
}

template<typename TIN>
__global__ __launch_bounds__(256) void gemm_mfma(const TIN* __restrict__ in,
                                                 const _Float16* __restrict__ wt,
                                                 _Float16* __restrict__ out) {
    __shared__ h4 Wl[4096];  // 32 KB swizzled W^T
    {
        const float4* src = (const float4*)wt;
        float4* dst = (float4*)Wl;
        #pragma unroll
        for (int i = 0; i < 8; ++i) dst[threadIdx.x + i * 256] = src[threadIdx.x + i * 256];
    }
    __syncthreads();

    const int wave = threadIdx.x >> 6;
    const int lane = threadIdx.x & 63;
    const int m0 = blockIdx.x * 64 + wave * 16;
    if (m0 >= N_NODES) return;

    const int row = lane & 15;   // m-offset (B col) / n-offset (A row)
    const int g   = lane >> 4;   // k-group
    const int m   = m0 + row;
    const TIN* arow = in + (size_t)m * DIM;

    f32x4 acc[8] = {};  // 8 n-tiles of 16 cols

    #pragma unroll
    for (int kc = 0; kc < 8; ++kc) {
        const int k = kc * 16 + g * 4;
        const h4 bfrag = loadfrag(arow + k);        // B[k..k+3][m]
        const int u = kc * 4 + g;
        #pragma unroll
        for (int nb = 0; nb < 8; ++nb) {
            const int n = nb * 16 + row;
            const h4 afrag = Wl[n * 32 + (u ^ (n & 31))];  // A[n][k..k+3]
            acc[nb] = __builtin_amdgcn_mfma_f32_16x16x16f16(afrag, bfrag, acc[nb], 0, 0, 0);
        }
    }

    _Float16* orow = out + (size_t)m * DIM;
    #pragma unroll
    for (int nb = 0; nb < 8; ++nb) {
        h4 v;
        v.x = (_Float16)acc[nb].x; v.y = (_Float16)acc[nb].y;
        v.z = (_Float16)acc[nb].z; v.w = (_Float16)acc[nb].w;
        ((h4*)orow)[nb * 4 + g] = v;   // cols nb*16 + g*4 .. +3
    }
}

// ---------------- fused aggregate + bias + relu ----------------

__global__ __launch_bounds__(256) void gather_agg(const _Float16* __restrict__ hw,
                                                  const float* __restrict__ dinv,
                                                  const int* __restrict__ off,
                                                  const EdgeRec* __restrict__ csr,
                                                  const float* __restrict__ bias,
                                                  _Float16* __restrict__ hout) {
    const int i = (blockIdx.x * blockDim.x + threadIdx.x) >> 6;  // node = wave id
    if (i >= N_NODES) return;
    const int lane = threadIdx.x & 63;
    const int q   = lane >> 4;   // edge stream 0..3
    const int sub = lane & 15;   // dims sub*8 .. sub*8+7
    const h8* hw8 = (const h8*)hw;  // row stride = 16 h8 units

    const int beg = off[i], end = off[i + 1];
    float accf[8] = {0.f, 0.f, 0.f, 0.f, 0.f, 0.f, 0.f, 0.f};

    if (q == 3) {  // self-loop message handled by stream 3
        float di = dinv[i];
        float w = di * di;
        h8 v = hw8[(size_t)i * 16 + sub];
        #pragma unroll
        for (int d = 0; d < 8; ++d) accf[d] = w * (float)v[d];
    }

    int j = beg + q;
    for (; j + 4 < end; j += 8) {
        EdgeRec e0 = csr[j];
        EdgeRec e1 = csr[j + 4];
        h8 v0 = hw8[(size_t)e0.s * 16 + sub];
        h8 v1 = hw8[(size_t)e1.s * 16 + sub];
        #pragma unroll
        for (int d = 0; d < 8; ++d) accf[d] += e0.w * (float)v0[d] + e1.w * (float)v1[d];
    }
    for (; j < end; j += 4) {
        EdgeRec e0 = csr[j];
        h8 v0 = hw8[(size_t)e0.s * 16 + sub];
        #pragma unroll
        for (int d = 0; d < 8; ++d) accf[d] += e0.w * (float)v0[d];
    }

    #pragma unroll
    for (int d = 0; d < 8; ++d) {
        float a = accf[d];
        a += __shfl_xor(a, 16);
        a += __shfl_xor(a, 32);
        accf[d] = a;
    }

    if (q == 0) {
        const float4 b0 = *(const float4*)&bias[sub * 8];
        const float4 b1 = *(const float4*)&bias[sub * 8 + 4];
        h8 v;
        v[0] = (_Float16)fmaxf(accf[0] + b0.x, 0.0f);
        v[1] = (_Float16)fmaxf(accf[1] + b0.y, 0.0f);
        v[2] = (_Float16)fmaxf(accf[2] + b0.z, 0.0f);
        v[3] = (_Float16)fmaxf(accf[3] + b0.w, 0.0f);
        v[4] = (_Float16)fmaxf(accf[4] + b1.x, 0.0f);
        v[5] = (_Float16)fmaxf(accf[5] + b1.y, 0.0f);
        v[6] = (_Float16)fmaxf(accf[6] + b1.z, 0.0f);
        v[7] = (_Float16)fmaxf(accf[7] + b1.w, 0.0f);
        ((h8*)hout)[(size_t)i * 16 + sub] = v;
    }
}

// ---------------- chunked segmented pool (batch sorted) ----------------
// 782 blocks x 128 rows; 256 thr = 8 row-groups x 32 lanes (h4 = 8B/lane).
// Register-accumulate per graph run; flush 4 atomicAdds on graph change.

__global__ __launch_bounds__(256) void pool_chunk(const _Float16* __restrict__ h,
                                                  const int* __restrict__ batch,
                                                  float* __restrict__ pooled) {
    const int base = blockIdx.x * PCHUNK;
    const int t = threadIdx.x;
    const int lane4 = t & 31;    // dims lane4*4 .. +3
    const int rgrp = t >> 5;     // 0..7
    const h4* hp = (const h4*)h; // row stride 32

    float a0 = 0.f, a1 = 0.f, a2 = 0.f, a3 = 0.f;
    int cur = -1;
    const int rend = (base + PCHUNK < N_NODES) ? base + PCHUNK : N_NODES;
    for (int r = base + rgrp; r < rend; r += 8) {
        int b = batch[r];
        if (b != cur) {
            if (cur >= 0) {
                float* pp = &pooled[cur * DIM + lane4 * 4];
                atomicAdd(pp + 0, a0); atomicAdd(pp + 1, a1);
                atomicAdd(pp + 2, a2); atomicAdd(pp + 3, a3);
            }
            cur = b; a0 = a1 = a2 = a3 = 0.f;
        }
        h4 v = hp[(size_t)r * 32 + lane4];
        a0 += (float)v.x; a1 += (float)v.y; a2 += (float)v.z; a3 += (float)v.w;
    }
    if (cur >= 0) {
        float* pp = &pooled[cur * DIM + lane4 * 4];
        atomicAdd(pp + 0, a0); atomicAdd(pp + 1, a1);
        atomicAdd(pp + 2, a2); atomicAdd(pp + 3, a3);
    }
}

// ---------------- head ----------------

__global__ void mlp_head(const float* __restrict__ pooled, const float* __restrict__ Wm,
                         const float* __restrict__ bm, float* __restrict__ out) {
    int t = blockIdx.x * blockDim.x + threadIdx.x;
    if (t >= N_GRAPHS * N_OUT) return;
    int b = t / N_OUT;
    int o = t % N_OUT;
    float acc = bm[o];
    #pragma unroll 8
    for (int k = 0; k < DIM; ++k) acc += pooled[b * DIM + k] * Wm[k * N_OUT + o];
    out[t] = acc;
}

// ---------------- launch ----------------

extern "C" void kernel_launch(void* const* d_in, const int* in_sizes, int n_in,
                              void* d_out, int out_size, void* d_ws, size_t ws_size,
                              hipStream_t stream) {
    const float* x     = (const float*)d_in[0];
    const int*   ei    = (const int*)d_in[1];
    const int*   batch = (const int*)d_in[2];
    const float* Ws    = (const float*)d_in[3];
    const float* bs    = (const float*)d_in[4];
    const float* Wm    = (const float*)d_in[5];
    const float* bm    = (const float*)d_in[6];
    float* out = (float*)d_out;

    // workspace carve-up (16B aligned regions; cnt+cursor adjacent for one memset)
    char* p = (char*)d_ws;
    int*      cnt     = (int*)p;        p += N_NODES * 4;
    int*      cursor  = (int*)p;        p += N_NODES * 4;
    float*    dinv    = (float*)p;      p += N_NODES * 4;
    int*      csr_off = (int*)p;        p += (N_NODES + 16) * 4;
    int*      bsum    = (int*)p;        p += 128 * 4;
    _Float16* wt      = (_Float16*)p;   p += (size_t)N_LAYERS * DIM * DIM * 2;  // swizzled W^T fp16
    EdgeRec*  csr     = (EdgeRec*)p;    p += (size_t)N_EDGES * 8;
    _Float16* bufA    = (_Float16*)p;   p += (size_t)N_NODES * DIM * 2;  // hw
    _Float16* bufB    = (_Float16*)p;   p += (size_t)N_NODES * DIM * 2;  // h
    float*    pooled  = (float*)p;      p += N_GRAPHS * DIM * 4;

    const int nnode_blk = (N_NODES + 255) / 256;
    const int nedge_blk = (N_EDGES + 255) / 256;

    hipMemsetAsync(cnt, 0, N_NODES * 8, stream);  // cnt + cursor
    hipMemsetAsync(pooled, 0, N_GRAPHS * DIM * 4, stream);

    hist_dst<<<nedge_blk, 256, 0, stream>>>(ei, cnt);
    make_dinv<<<nnode_blk, 256, 0, stream>>>(cnt, dinv);
    wt_prep<<<(N_LAYERS * DIM * 32 + 255) / 256, 256, 0, stream>>>(Ws, wt);

    scan1<<<N_SCAN_BLKS, 256, 0, stream>>>(cnt, csr_off, bsum);
    scan2<<<1, 64, 0, stream>>>(bsum);
    scan3<<<nnode_blk, 256, 0, stream>>>(csr_off, bsum);

    fill_csr<<<nedge_blk, 256, 0, stream>>>(ei, dinv, csr_off, cursor, csr);

    const int gemm_grid = (N_NODES + 63) / 64;
    const int gather_grid = (N_NODES * 64 + 255) / 256;
    for (int l = 0; l < N_LAYERS; ++l) {
        if (l == 0) gemm_mfma<float><<<gemm_grid, 256, 0, stream>>>(x, wt, bufA);
        else        gemm_mfma<_Float16><<<gemm_grid, 256, 0, stream>>>(bufB, wt + (size_t)l * DIM * DIM, bufA);
        gather_agg<<<gather_grid, 256, 0, stream>>>(bufA, dinv, csr_off, csr, bs + l * DIM, bufB);
    }

    pool_chunk<<<(N_NODES + PCHUNK - 1) / PCHUNK, 256, 0, stream>>>(bufB, batch, pooled);
    mlp_head<<<(N_GRAPHS * N_OUT + 255) / 256, 256, 0, stream>>>(pooled, Wm, bm, out);
}